// Round 10
// baseline (704.767 us; speedup 1.0000x reference)
//
#include <hip/hip_runtime.h>
#include <cstdint>
#include <cstddef>

typedef unsigned short u16;
typedef unsigned int u32;

typedef unsigned short u16x8 __attribute__((ext_vector_type(8)));
typedef __bf16 bf16x8 __attribute__((ext_vector_type(8)));
typedef float f32x4 __attribute__((ext_vector_type(4)));
typedef float f32x8 __attribute__((ext_vector_type(8)));

#define NB   128
#define NL   192
#define NTOK (NB * NL)   // 24576
#define DIM  512
#define HID  2048
#define PM   96          // fused-FFN panel rows; NTOK/PM = 256 blocks = CU count

static __device__ __forceinline__ float bf2f(u16 h) {
    union { u32 u; float f; } v; v.u = ((u32)h) << 16; return v.f;
}
static __device__ __forceinline__ u16 f2bf(float f) {
    union { float f; u32 u; } v; v.f = f;
    u32 u = v.u + 0x7FFF + ((v.u >> 16) & 1);  // RNE
    return (u16)(u >> 16);
}

// -------- weight transpose + cast: in f32 (K,N) -> out bf16 (N,K) --------
__global__ void transpose_f2b(const float* __restrict__ in, u16* __restrict__ out,
                              int K, int N) {
    __shared__ float tile[32][33];
    int tx = threadIdx.x & 31, ty = threadIdx.x >> 5;  // 32 x 8
    int n0 = blockIdx.x * 32, k0 = blockIdx.y * 32;
#pragma unroll
    for (int i = 0; i < 4; i++)
        tile[ty + i * 8][tx] = in[(size_t)(k0 + ty + i * 8) * N + n0 + tx];
    __syncthreads();
#pragma unroll
    for (int i = 0; i < 4; i++)
        out[(size_t)(n0 + ty + i * 8) * K + k0 + tx] = f2bf(tile[tx][ty + i * 8]);
}

// -------- embedding: emb[t=l*B+b][d] = sum of 5 f32 tables ----
static __device__ __forceinline__ void add8f(float* acc, const float* p) {
    f32x8 v = *(const f32x8*)p;
#pragma unroll
    for (int i = 0; i < 8; i++) acc[i] += v[i];
}

__global__ void embed_kernel(const int* __restrict__ element, const int* __restrict__ aroma,
                             const int* __restrict__ charge, const int* __restrict__ segment,
                             const float* __restrict__ pe, const float* __restrict__ E_elem,
                             const float* __restrict__ E_charge, const float* __restrict__ E_aroma,
                             const float* __restrict__ E_seg,
                             float* __restrict__ emb32, u16* __restrict__ emb16) {
    int t = blockIdx.x * 4 + (threadIdx.x >> 6);  // one wave per token
    int lane = threadIdx.x & 63;
    int l = t >> 7, b = t & 127;                  // t = l*128 + b
    int d = lane * 8;
    int idx = b * NL + l;
    int e = element[idx];
    int a = aroma[idx];
    int c = charge[idx] + 6;
    int s = segment[idx];
    float acc[8] = {0, 0, 0, 0, 0, 0, 0, 0};
    add8f(acc, E_elem  + (size_t)e * DIM + d);
    add8f(acc, pe      + (size_t)l * DIM + d);
    add8f(acc, E_aroma + (size_t)a * DIM + d);
    add8f(acc, E_charge+ (size_t)c * DIM + d);
    add8f(acc, E_seg   + (size_t)s * DIM + d);
    f32x8 o32; u16x8 o16;
#pragma unroll
    for (int i = 0; i < 8; i++) { o32[i] = acc[i]; o16[i] = f2bf(acc[i]); }
    *(f32x8*)(emb32 + (size_t)t * DIM + d) = o32;
    *(u16x8*)(emb16 + (size_t)t * DIM + d) = o16;
}

// ======================= fused FFN (+optional W5) =======================
// Computes, per 96-row panel of X [M][512] bf16:
//   h_j  = relu(X @ WaT_j^T + ba_j)   (j = 8 slices of 256 hidden cols)
//   acc2 = sum_j h_j @ WbT_j^T        (output 96x512)
//   out  = acc2 + bb + resid          (resid = resid32 f32, or X itself)
//   if WcT: xb = out (kept in LDS); OUT = xb @ WcT^T + bc   (W5 fold)
// The 2048-wide hidden NEVER touches HBM (was 400 MB of round-trip traffic
// across 4 dispatches -- the invariant ~90 us/dispatch cost that 8 schedule/
// layout variants could not move).
// Structure: 256 blocks (full CU fill), 8 waves (2M x 4N), 1 block/CU.
//   x-panel staged ONCE to LDS (96 KB, GLL + proven chunk-XOR swizzle).
//   Weights (L2-resident: Wa+Wb = 4 MB/XCD) are read as MFMA B-fragments
//   directly global->VGPR: lanes (fr,fq) -> 16 full 64B lines per frag-load.
//   h via LDS [96][264] (pad-264: 2-way read conflict = free).
//   2 __syncthreads per j; GEMM interiors barrier-free (compiler-scheduled).
__global__ __launch_bounds__(512, 2) void ffn_fused(
    const u16* __restrict__ X,          // [M][512] bf16 row-major
    const float* __restrict__ resid32,  // [M][512] f32 (emb32) or nullptr
    const u16* __restrict__ WaT,        // [2048][512] bf16 (W1T/W3T)
    const float* __restrict__ ba,       // [2048]
    const u16* __restrict__ WbT,        // [512][2048] bf16 (W2T/W4T)
    const float* __restrict__ bb,       // [512]
    const u16* __restrict__ WcT,        // [512][512] bf16 (W5T) or nullptr
    const float* __restrict__ bc,       // [512] or nullptr
    u16* __restrict__ OUT) {            // [M][512] bf16
    __shared__ __align__(16) u16 xs[PM * 512];   // 96 KB swizzled x (later xb)
    __shared__ __align__(16) u16 hs[PM * 264];   // 49.5 KB h / out staging

    const int tid  = threadIdx.x;
    const int wave = tid >> 6;
    const int lane = tid & 63;
    const int fr   = lane & 15;
    const int fq   = lane >> 4;
    const int wmh  = wave >> 2;      // 0..1 : 48-row half
    const int wnq  = wave & 3;       // 0..3

    // XCD swizzle (nwg = 256, %8==0)
    const int bid = blockIdx.x;
    const int wg  = (bid & 7) * (gridDim.x >> 3) + (bid >> 3);
    const int m0  = wg * PM;

    // ---- stage x-panel into LDS (once): 6144 chunks of 16B, 12/thread ----
    // xs[row][c] holds global chunk c^(row&7)  (pre-swizzled source, linear
    // GLL dest: per-wave dst = base + lane*16B).
#define GLL(gp, lp) __builtin_amdgcn_global_load_lds(                            \
        (const __attribute__((address_space(1))) void*)(gp),                     \
        (__attribute__((address_space(3))) void*)(lp), 16, 0, 0)
#pragma unroll
    for (int g = 0; g < 12; ++g) {
        int chunk = g * 512 + tid;
        int row = chunk >> 6, c = chunk & 63;
        GLL(X + (size_t)(m0 + row) * 512 + ((c ^ (row & 7)) * 8), &xs[chunk * 8]);
    }
#undef GLL
    asm volatile("s_waitcnt vmcnt(0)" ::: "memory");
    __syncthreads();

    // swizzled x-read: logical k-chunk q (0..63) of row -> position q^(row&7).
    // row&7 == fr&7 for all A-rows (48,16 are multiples of 8).
#define XRD(row, q) (*(const bf16x8*)&xs[(row) * 512 + (((q) ^ ((row) & 7)) * 8)])

    f32x4 acc2[3][8] = {};

    for (int j = 0; j < 8; ++j) {
        // ---------- GEMM-1: acc1[96x256 slice] = x @ WaT_j^T ----------
        f32x4 acc1[3][4] = {};
        const u16* Wa = WaT + (size_t)(j * 256 + wnq * 64) * 512;
#pragma unroll
        for (int kt = 0; kt < 8; ++kt) {
            bf16x8 bfr[4][2], afr[3][2];
#pragma unroll
            for (int j2 = 0; j2 < 4; ++j2)
#pragma unroll
                for (int s = 0; s < 2; ++s)
                    bfr[j2][s] = *(const bf16x8*)(Wa + (size_t)(j2 * 16 + fr) * 512
                                                  + kt * 64 + s * 32 + fq * 8);
#pragma unroll
            for (int i = 0; i < 3; ++i) {
                int row = wmh * 48 + i * 16 + fr;
#pragma unroll
                for (int s = 0; s < 2; ++s)
                    afr[i][s] = XRD(row, kt * 8 + s * 4 + fq);
            }
            __builtin_amdgcn_s_setprio(1);
#pragma unroll
            for (int i = 0; i < 3; ++i)
#pragma unroll
                for (int j2 = 0; j2 < 4; ++j2)
#pragma unroll
                    for (int s = 0; s < 2; ++s)
                        acc1[i][j2] = __builtin_amdgcn_mfma_f32_16x16x32_bf16(
                            afr[i][s], bfr[j2][s], acc1[i][j2], 0, 0, 0);
            __builtin_amdgcn_s_setprio(0);
        }
        // ---------- h-write: relu + ba ----------
        __syncthreads();   // all waves done reading h(j-1)
#pragma unroll
        for (int j2 = 0; j2 < 4; ++j2) {
            float bv = ba[j * 256 + wnq * 64 + j2 * 16 + fr];
#pragma unroll
            for (int i = 0; i < 3; ++i)
#pragma unroll
                for (int r = 0; r < 4; ++r)
                    hs[(wmh * 48 + i * 16 + fq * 4 + r) * 264 + wnq * 64 + j2 * 16 + fr]
                        = f2bf(fmaxf(acc1[i][j2][r] + bv, 0.0f));
        }
        __syncthreads();   // h(j) visible to all
        // ---------- GEMM-2: acc2 += h_j @ WbT_j^T (two 4-col batches) ----
        const u16* Wb = WbT + (size_t)(wnq * 128) * 2048 + j * 256;
#pragma unroll
        for (int k2t = 0; k2t < 4; ++k2t) {
            bf16x8 afr[3][2];
#pragma unroll
            for (int i = 0; i < 3; ++i)
#pragma unroll
                for (int s = 0; s < 2; ++s)
                    afr[i][s] = *(const bf16x8*)&hs[(wmh * 48 + i * 16 + fr) * 264
                                                    + k2t * 64 + s * 32 + fq * 8];
#pragma unroll
            for (int hb = 0; hb < 2; ++hb) {
                bf16x8 bfr[4][2];
#pragma unroll
                for (int j2 = 0; j2 < 4; ++j2)
#pragma unroll
                    for (int s = 0; s < 2; ++s)
                        bfr[j2][s] = *(const bf16x8*)(Wb + (size_t)((hb * 4 + j2) * 16 + fr) * 2048
                                                      + k2t * 64 + s * 32 + fq * 8);
                __builtin_amdgcn_s_setprio(1);
#pragma unroll
                for (int i = 0; i < 3; ++i)
#pragma unroll
                    for (int j2 = 0; j2 < 4; ++j2)
#pragma unroll
                        for (int s = 0; s < 2; ++s)
                            acc2[i][hb * 4 + j2] = __builtin_amdgcn_mfma_f32_16x16x32_bf16(
                                afr[i][s], bfr[j2][s], acc2[i][hb * 4 + j2], 0, 0, 0);
                __builtin_amdgcn_s_setprio(0);
            }
        }
    }

    if (!WcT) {
        // ---------- epilogue (kernel 1): OUT = acc2 + bb + resid32 ----------
#pragma unroll
        for (int p = 0; p < 2; ++p) {
            __syncthreads();
            if ((wnq >> 1) == p) {
#pragma unroll
                for (int j2 = 0; j2 < 8; ++j2) {
                    int col = wnq * 128 + j2 * 16 + fr;
                    float bv = bb[col];
#pragma unroll
                    for (int i = 0; i < 3; ++i)
#pragma unroll
                        for (int r = 0; r < 4; ++r) {
                            int row = wmh * 48 + i * 16 + fq * 4 + r;
                            float v = acc2[i][j2][r] + bv
                                    + resid32[(size_t)(m0 + row) * 512 + col];
                            hs[row * 264 + (col - p * 256)] = f2bf(v);
                        }
                }
            }
            __syncthreads();
#pragma unroll
            for (int g = 0; g < 6; ++g) {
                int chunk = g * 512 + tid;           // 3072 chunks = 96x256/8
                int row = chunk >> 5, c = chunk & 31;
                *(u16x8*)(OUT + (size_t)(m0 + row) * 512 + p * 256 + c * 8) =
                    *(const u16x8*)&hs[row * 264 + c * 8];
            }
        }
        return;
    }

    // ---------- kernel 2: xb = acc2 + bb + x (resid from LDS), into xs ----
    __syncthreads();   // all GEMM-1/2 reads of xs/hs complete
#pragma unroll
    for (int j2 = 0; j2 < 8; ++j2) {
        int col = wnq * 128 + j2 * 16 + fr;
        float bv = bb[col];
        int q = col >> 3, lo = col & 7;
#pragma unroll
        for (int i = 0; i < 3; ++i)
#pragma unroll
            for (int r = 0; r < 4; ++r) {
                int row = wmh * 48 + i * 16 + fq * 4 + r;
                int xi = row * 512 + ((q ^ (row & 7)) * 8) + lo;
                float v = acc2[i][j2][r] + bv + bf2f(xs[xi]);
                xs[xi] = f2bf(v);      // element owned by exactly this lane
            }
    }
    __syncthreads();   // xb visible
    // ---------- GEMM-3: OUT = xb @ WcT^T + bc ----------
    f32x4 acc3[3][8] = {};
#pragma unroll
    for (int kt = 0; kt < 8; ++kt) {
        bf16x8 afr[3][2];
#pragma unroll
        for (int i = 0; i < 3; ++i) {
            int row = wmh * 48 + i * 16 + fr;
#pragma unroll
            for (int s = 0; s < 2; ++s)
                afr[i][s] = XRD(row, kt * 8 + s * 4 + fq);
        }
#pragma unroll
        for (int hb = 0; hb < 2; ++hb) {
            bf16x8 bfr[4][2];
#pragma unroll
            for (int j2 = 0; j2 < 4; ++j2)
#pragma unroll
                for (int s = 0; s < 2; ++s)
                    bfr[j2][s] = *(const bf16x8*)(WcT + (size_t)(wnq * 128 + (hb * 4 + j2) * 16 + fr) * 512
                                                  + kt * 64 + s * 32 + fq * 8);
            __builtin_amdgcn_s_setprio(1);
#pragma unroll
            for (int i = 0; i < 3; ++i)
#pragma unroll
                for (int j2 = 0; j2 < 4; ++j2)
#pragma unroll
                    for (int s = 0; s < 2; ++s)
                        acc3[i][hb * 4 + j2] = __builtin_amdgcn_mfma_f32_16x16x32_bf16(
                            afr[i][s], bfr[j2][s], acc3[i][hb * 4 + j2], 0, 0, 0);
            __builtin_amdgcn_s_setprio(0);
        }
    }
    // epilogue-3: OUT = acc3 + bc (no resid)
#pragma unroll
    for (int p = 0; p < 2; ++p) {
        __syncthreads();
        if ((wnq >> 1) == p) {
#pragma unroll
            for (int j2 = 0; j2 < 8; ++j2) {
                int col = wnq * 128 + j2 * 16 + fr;
                float bv = bc[col];
#pragma unroll
                for (int i = 0; i < 3; ++i)
#pragma unroll
                    for (int r = 0; r < 4; ++r) {
                        int row = wmh * 48 + i * 16 + fq * 4 + r;
                        hs[row * 264 + (col - p * 256)] = f2bf(acc3[i][j2][r] + bv);
                    }
            }
        }
        __syncthreads();
#pragma unroll
        for (int g = 0; g < 6; ++g) {
            int chunk = g * 512 + tid;
            int row = chunk >> 5, c = chunk & 31;
            *(u16x8*)(OUT + (size_t)(m0 + row) * 512 + p * 256 + c * 8) =
                *(const u16x8*)&hs[row * 264 + c * 8];
        }
    }
#undef XRD
}

// -------- aggregation + final residual (in-place on d_out, f32) --------
// out[t=l*B+b][d] = emb32[t][d] + sum_m (bond[b,l,m]!=l) * msg[bond*B+b][d]
__global__ void agg_kernel(const float* __restrict__ emb32, const u16* __restrict__ msg,
                           const int* __restrict__ bond, float* __restrict__ out) {
    int t = blockIdx.x * 4 + (threadIdx.x >> 6);  // one wave per token
    int lane = threadIdx.x & 63;
    int l = t >> 7, b = t & 127;
    int d = lane * 8;
    float acc[8];
    {
        f32x8 v = *(const f32x8*)(emb32 + (size_t)t * DIM + d);
#pragma unroll
        for (int i = 0; i < 8; i++) acc[i] = v[i];
    }
    const int* bp = bond + ((size_t)b * NL + l) * 6;
#pragma unroll
    for (int m = 0; m < 6; m++) {
        int j = bp[m];
        if (j != l) {  // wave-uniform branch
            u16x8 g = *(const u16x8*)(msg + ((size_t)j * NB + b) * DIM + d);
#pragma unroll
            for (int i = 0; i < 8; i++) acc[i] += bf2f(g[i]);
        }
    }
    f32x8 o;
#pragma unroll
    for (int i = 0; i < 8; i++) o[i] = acc[i];
    *(f32x8*)(out + (size_t)t * DIM + d) = o;
}

extern "C" void kernel_launch(void* const* d_in, const int* in_sizes, int n_in,
                              void* d_out, int out_size, void* d_ws, size_t ws_size,
                              hipStream_t stream) {
    const int* element = (const int*)d_in[0];
    const int* bond    = (const int*)d_in[1];
    const int* aroma   = (const int*)d_in[2];
    const int* charge  = (const int*)d_in[3];
    const int* segment = (const int*)d_in[4];
    const float* pe      = (const float*)d_in[5];
    const float* E_elem  = (const float*)d_in[6];
    const float* E_charge= (const float*)d_in[7];
    const float* E_aroma = (const float*)d_in[8];
    const float* E_seg   = (const float*)d_in[9];
    const float* W1 = (const float*)d_in[10];
    const float* b1 = (const float*)d_in[11];
    const float* W2 = (const float*)d_in[12];
    const float* b2 = (const float*)d_in[13];
    const float* W3 = (const float*)d_in[14];
    const float* b3 = (const float*)d_in[15];
    const float* W4 = (const float*)d_in[16];
    const float* b4 = (const float*)d_in[17];
    const float* W5 = (const float*)d_in[18];
    const float* b5 = (const float*)d_in[19];

    // f32 emb lives in d_out (50 MiB); agg rewrites d_out in place at the end.
    float* emb32 = (float*)d_out;

    // dynamic ws layout — never exceed ws_size
    char* ws = (char*)d_ws;
    size_t woff = 0;
    auto take = [&](size_t bytes) -> u16* {
        u16* p = (u16*)(ws + woff);
        woff += (bytes + 255) & ~(size_t)255;
        return p;
    };
    u16* W1T = take((size_t)HID * DIM * 2);   // 2048x512 bf16
    u16* W2T = take((size_t)DIM * HID * 2);   // 512x2048
    u16* W3T = take((size_t)HID * DIM * 2);
    u16* W4T = take((size_t)DIM * HID * 2);
    u16* W5T = take((size_t)DIM * DIM * 2);
    u16* emb16 = take((size_t)NTOK * DIM * 2);  // 24 MiB
    u16* xa    = take((size_t)NTOK * DIM * 2);  // 24 MiB
    u16* msg   = take((size_t)NTOK * DIM * 2);  // 24 MiB

    // weight transposes + cast: f32 (K,N) -> bf16 (N,K)
    transpose_f2b<<<dim3(HID / 32, DIM / 32), 256, 0, stream>>>(W1, W1T, DIM, HID);
    transpose_f2b<<<dim3(DIM / 32, HID / 32), 256, 0, stream>>>(W2, W2T, HID, DIM);
    transpose_f2b<<<dim3(HID / 32, DIM / 32), 256, 0, stream>>>(W3, W3T, DIM, HID);
    transpose_f2b<<<dim3(DIM / 32, HID / 32), 256, 0, stream>>>(W4, W4T, HID, DIM);
    transpose_f2b<<<dim3(DIM / 32, DIM / 32), 256, 0, stream>>>(W5, W5T, DIM, DIM);

    embed_kernel<<<NTOK / 4, 256, 0, stream>>>(element, aroma, charge, segment, pe,
                                               E_elem, E_charge, E_aroma, E_seg,
                                               emb32, emb16);

    // fused MLP: xa = emb32 + relu(emb@W1+b1)@W2+b2
    //            msg = (xa + relu(xa@W3+b3)@W4+b4) @ W5 + b5
    ffn_fused<<<NTOK / PM, 512, 0, stream>>>(emb16, emb32, W1T, b1, W2T, b2,
                                             nullptr, nullptr, xa);
    ffn_fused<<<NTOK / PM, 512, 0, stream>>>(xa, nullptr, W3T, b3, W4T, b4,
                                             W5T, b5, msg);

    agg_kernel<<<NTOK / 4, 256, 0, stream>>>(emb32, msg, bond, (float*)d_out);
}